// Round 1
// baseline (288.987 us; speedup 1.0000x reference)
//
#include <hip/hip_runtime.h>

#define SQ2F 0.70710678118654752440f

__device__ __forceinline__ int symref(int t, int L) {
    // single reflection is sufficient for all index ranges in this problem
    if (t < 0) t = -1 - t;
    if (t >= L) t = 2 * L - 1 - t;
    return t;
}

// ---------------------------------------------------------------------------
// Level 1 (full resolution): fused rowfilter (h0o/h1o, recomputed per thread),
// colfilter, q2c, band packing. One thread per (bc, i, j) output 2x2 block.
//   x   : (BC, 256, 256)
//   ll  : (BC, 256, 256)   full-res lowpass for level 2
//   yh0 : (BC, 6, 128, 128, 2)
// ---------------------------------------------------------------------------
__global__ __launch_bounds__(256) void level1_fused(
    const float* __restrict__ x,
    const float* __restrict__ h0o,  // 5 taps
    const float* __restrict__ h1o,  // 7 taps
    float* __restrict__ ll,
    float* __restrict__ yh0,
    int BC)
{
    const int H = 256, W = 256, H2 = 128, W2 = 128;
    int idx = blockIdx.x * blockDim.x + threadIdx.x;
    int total = BC * H2 * W2;
    if (idx >= total) return;
    int j  = idx & (W2 - 1);
    int i  = (idx >> 7) & (H2 - 1);
    int bc = idx >> 14;

    float f0[5], f1[7];
    #pragma unroll
    for (int t = 0; t < 5; t++) f0[t] = h0o[t];
    #pragma unroll
    for (int t = 0; t < 7; t++) f1[t] = h1o[t];

    const float* xb = x + (size_t)bc * H * W;

    // columns 2j-3 .. 2j+4 (union of 5-tap and 7-tap row-filter windows)
    int cidx[8];
    #pragma unroll
    for (int c = 0; c < 8; c++) cidx[c] = symref(2 * j - 3 + c, W);

    // row filters for rows 2i-3 .. 2i+4 at cols 2j, 2j+1
    float lo0[8], lo1[8], hi0[8], hi1[8];
    #pragma unroll
    for (int r = 0; r < 8; r++) {
        int row = symref(2 * i - 3 + r, H);
        const float* xr = xb + (size_t)row * W;
        float xv[8];
        #pragma unroll
        for (int c = 0; c < 8; c++) xv[c] = xr[cidx[c]];
        // lo[c] = sum_t f0[t] * x[c + 2 - t] ; hi[c] = sum_t f1[t] * x[c + 3 - t]
        float l0 = 0.f, l1 = 0.f, h0 = 0.f, h1 = 0.f;
        #pragma unroll
        for (int t = 0; t < 5; t++) { l0 += f0[t] * xv[5 - t]; l1 += f0[t] * xv[6 - t]; }
        #pragma unroll
        for (int t = 0; t < 7; t++) { h0 += f1[t] * xv[6 - t]; h1 += f1[t] * xv[7 - t]; }
        lo0[r] = l0; lo1[r] = l1; hi0[r] = h0; hi1[r] = h1;
    }

    // column filters; buffer index for raw row (2i + m2 - t) is (m2 + 3 - t)
    float ll00=0,ll01=0,ll10=0,ll11=0, hl00=0,hl01=0,hl10=0,hl11=0;
    #pragma unroll
    for (int t = 0; t < 5; t++) {
        ll00 += f0[t]*lo0[5-t]; ll01 += f0[t]*lo1[5-t];
        ll10 += f0[t]*lo0[6-t]; ll11 += f0[t]*lo1[6-t];
        hl00 += f0[t]*hi0[5-t]; hl01 += f0[t]*hi1[5-t];
        hl10 += f0[t]*hi0[6-t]; hl11 += f0[t]*hi1[6-t];
    }
    float lh00=0,lh01=0,lh10=0,lh11=0, hh00=0,hh01=0,hh10=0,hh11=0;
    #pragma unroll
    for (int t = 0; t < 7; t++) {
        lh00 += f1[t]*lo0[6-t]; lh01 += f1[t]*lo1[6-t];
        lh10 += f1[t]*lo0[7-t]; lh11 += f1[t]*lo1[7-t];
        hh00 += f1[t]*hi0[6-t]; hh01 += f1[t]*hi1[6-t];
        hh10 += f1[t]*hi0[7-t]; hh11 += f1[t]*hi1[7-t];
    }

    // write full-res ll
    float* llb = ll + (size_t)bc * H * W;
    llb[(size_t)(2*i)*W   + 2*j]     = ll00;
    llb[(size_t)(2*i)*W   + 2*j + 1] = ll01;
    llb[(size_t)(2*i+1)*W + 2*j]     = ll10;
    llb[(size_t)(2*i+1)*W + 2*j + 1] = ll11;

    // q2c + band packing: bands [15,45,75,105,135,165] from lh,hh,hl
    float* yb = yh0 + (size_t)bc * 6 * H2 * W2 * 2;
    size_t pix = ((size_t)i * W2 + j) * 2;
    size_t bs  = (size_t)H2 * W2 * 2;
    {
        float a = SQ2F*lh00, b = SQ2F*lh01, c = SQ2F*lh10, d = SQ2F*lh11;
        yb[0*bs + pix] = a - d; yb[0*bs + pix + 1] = b + c;
        yb[5*bs + pix] = a + d; yb[5*bs + pix + 1] = b - c;
    }
    {
        float a = SQ2F*hh00, b = SQ2F*hh01, c = SQ2F*hh10, d = SQ2F*hh11;
        yb[1*bs + pix] = a - d; yb[1*bs + pix + 1] = b + c;
        yb[4*bs + pix] = a + d; yb[4*bs + pix + 1] = b - c;
    }
    {
        float a = SQ2F*hl00, b = SQ2F*hl01, c = SQ2F*hl10, d = SQ2F*hl11;
        yb[2*bs + pix] = a - d; yb[2*bs + pix + 1] = b + c;
        yb[3*bs + pix] = a + d; yb[3*bs + pix + 1] = b - c;
    }
}

// ---------------------------------------------------------------------------
// rowdfilt pair: lo = rowdfilt(X, h0b, h0a, False), hi = rowdfilt(X, h1b, h1a, True)
//   X       : (BC, R, C)
//   lo, hi  : (BC, R, C/2)
// One thread per (bc, r, n), n < C/4 producing output cols 2n, 2n+1 of both.
//   a[n] = sum_t ha[t] * X[sym(4n+11-2t)],  b[n] = sum_t hb[t] * X[sym(4n+10-2t)]
//   lowpass:  out[2n]=a, out[2n+1]=b ; highpass: out[2n]=b, out[2n+1]=a
// ---------------------------------------------------------------------------
__global__ __launch_bounds__(256) void rowdfilt_pair(
    const float* __restrict__ X,
    const float* __restrict__ h0a, const float* __restrict__ h0b,
    const float* __restrict__ h1a, const float* __restrict__ h1b,
    float* __restrict__ lo, float* __restrict__ hi,
    int BC, int R, int C)
{
    int C4 = C >> 2, C2 = C >> 1;
    int idx = blockIdx.x * blockDim.x + threadIdx.x;
    int total = BC * R * C4;
    if (idx >= total) return;
    int n  = idx % C4;
    int r  = (idx / C4) % R;
    int bc = idx / (C4 * R);

    const float* Xr = X + ((size_t)bc * R + r) * C;
    float v[20];
    #pragma unroll
    for (int c = 0; c < 20; c++) v[c] = Xr[symref(4 * n - 8 + c, C)];

    float aLo = 0.f, bLo = 0.f, aHi = 0.f, bHi = 0.f;
    #pragma unroll
    for (int t = 0; t < 10; t++) {
        float vo = v[19 - 2 * t];   // X[4n+11-2t]
        float ve = v[18 - 2 * t];   // X[4n+10-2t]
        aLo += h0b[t] * vo; bLo += h0a[t] * ve;
        aHi += h1b[t] * vo; bHi += h1a[t] * ve;
    }
    float* lor = lo + ((size_t)bc * R + r) * C2;
    float* hir = hi + ((size_t)bc * R + r) * C2;
    lor[2 * n] = aLo; lor[2 * n + 1] = bLo;   // lowpass
    hir[2 * n] = bHi; hir[2 * n + 1] = aHi;   // highpass
}

// ---------------------------------------------------------------------------
// coldfilt x4 + q2c + band packing.
//   lo, hi : (BC, R, C2)
//   llout  : (BC, R/2, C2)     (next-level ll, or final ll output)
//   yh     : (BC, 6, R/4, C2/2, 2)
// One thread per (bc, i, j), i < R/4, j < C2/2.
//   ll = coldfilt(lo, h0b, h0a, False), lh = coldfilt(lo, h1b, h1a, True)
//   hl = coldfilt(hi, h0b, h0a, False), hh = coldfilt(hi, h1b, h1a, True)
// ---------------------------------------------------------------------------
__global__ __launch_bounds__(256) void coldfilt_bands(
    const float* __restrict__ lo, const float* __restrict__ hi,
    const float* __restrict__ h0a, const float* __restrict__ h0b,
    const float* __restrict__ h1a, const float* __restrict__ h1b,
    float* __restrict__ llout,
    float* __restrict__ yh,
    int BC, int R, int C2)
{
    int R4 = R >> 2, Wq = C2 >> 1;
    int idx = blockIdx.x * blockDim.x + threadIdx.x;
    int total = BC * R4 * Wq;
    if (idx >= total) return;
    int j  = idx % Wq;
    int i  = (idx / Wq) % R4;
    int bc = idx / (Wq * R4);

    const float* lob = lo + (size_t)bc * R * C2;
    const float* hib = hi + (size_t)bc * R * C2;

    float ll_[2][2], lh_[2][2], hl_[2][2], hh_[2][2];
    #pragma unroll
    for (int cc = 0; cc < 2; cc++) {
        int col = 2 * j + cc;
        float a_ll=0,b_ll=0,a_lh=0,b_lh=0,a_hl=0,b_hl=0,a_hh=0,b_hh=0;
        float vl[20], vh[20];
        #pragma unroll
        for (int r = 0; r < 20; r++) {
            int row = symref(4 * i - 8 + r, R);
            vl[r] = lob[(size_t)row * C2 + col];
            vh[r] = hib[(size_t)row * C2 + col];
        }
        #pragma unroll
        for (int t = 0; t < 10; t++) {
            float vo_l = vl[19 - 2 * t], ve_l = vl[18 - 2 * t];
            float vo_h = vh[19 - 2 * t], ve_h = vh[18 - 2 * t];
            a_ll += h0b[t] * vo_l;  b_ll += h0a[t] * ve_l;
            a_lh += h1b[t] * vo_l;  b_lh += h1a[t] * ve_l;
            a_hl += h0b[t] * vo_h;  b_hl += h0a[t] * ve_h;
            a_hh += h1b[t] * vo_h;  b_hh += h1a[t] * ve_h;
        }
        ll_[0][cc] = a_ll; ll_[1][cc] = b_ll;  // lowpass: ev=a, od=b
        lh_[0][cc] = b_lh; lh_[1][cc] = a_lh;  // highpass: ev=b, od=a
        hl_[0][cc] = a_hl; hl_[1][cc] = b_hl;
        hh_[0][cc] = b_hh; hh_[1][cc] = a_hh;
    }

    // write next-level ll (rows 2i, 2i+1; cols 2j, 2j+1)
    float* llb = llout + (size_t)bc * (R >> 1) * C2;
    llb[(size_t)(2*i)*C2   + 2*j]     = ll_[0][0];
    llb[(size_t)(2*i)*C2   + 2*j + 1] = ll_[0][1];
    llb[(size_t)(2*i+1)*C2 + 2*j]     = ll_[1][0];
    llb[(size_t)(2*i+1)*C2 + 2*j + 1] = ll_[1][1];

    // q2c + bands
    float* yb = yh + (size_t)bc * 6 * R4 * Wq * 2;
    size_t pix = ((size_t)i * Wq + j) * 2;
    size_t bs  = (size_t)R4 * Wq * 2;
    {
        float a = SQ2F*lh_[0][0], b = SQ2F*lh_[0][1], c = SQ2F*lh_[1][0], d = SQ2F*lh_[1][1];
        yb[0*bs + pix] = a - d; yb[0*bs + pix + 1] = b + c;
        yb[5*bs + pix] = a + d; yb[5*bs + pix + 1] = b - c;
    }
    {
        float a = SQ2F*hh_[0][0], b = SQ2F*hh_[0][1], c = SQ2F*hh_[1][0], d = SQ2F*hh_[1][1];
        yb[1*bs + pix] = a - d; yb[1*bs + pix + 1] = b + c;
        yb[4*bs + pix] = a + d; yb[4*bs + pix + 1] = b - c;
    }
    {
        float a = SQ2F*hl_[0][0], b = SQ2F*hl_[0][1], c = SQ2F*hl_[1][0], d = SQ2F*hl_[1][1];
        yb[2*bs + pix] = a - d; yb[2*bs + pix + 1] = b + c;
        yb[3*bs + pix] = a + d; yb[3*bs + pix + 1] = b - c;
    }
}

extern "C" void kernel_launch(void* const* d_in, const int* in_sizes, int n_in,
                              void* d_out, int out_size, void* d_ws, size_t ws_size,
                              hipStream_t stream) {
    const float* x   = (const float*)d_in[0];
    const float* h0o = (const float*)d_in[1];
    const float* h1o = (const float*)d_in[2];
    const float* h0a = (const float*)d_in[3];
    const float* h0b = (const float*)d_in[4];
    const float* h1a = (const float*)d_in[5];
    const float* h1b = (const float*)d_in[6];
    float* out = (float*)d_out;

    const int BC = 8 * 16;  // 128

    // output layout (flat, return order): ll | yh0 | yh1 | yh2
    float* out_ll  = out;                        // 128*64*64          = 524288
    float* out_yh0 = out + 524288;               // 128*6*128*128*2    = 25165824
    float* out_yh1 = out + 25690112;             // 128*6*64*64*2      = 6291456
    float* out_yh2 = out + 31981568;             // 128*6*32*32*2      = 1572864

    // workspace: wsA = ll ping-pong (max 128*256*256 floats = 32 MiB)
    //            wsB/wsC = lo/hi (max 128*256*128 floats = 16 MiB each)
    float* wsA = (float*)d_ws;
    float* wsB = wsA + 8388608;
    float* wsC = wsB + 4194304;

    const int BLK = 256;

    // ---- level 1: x -> yh0, ll(256x256) in wsA
    {
        int total = BC * 128 * 128;
        level1_fused<<<(total + BLK - 1) / BLK, BLK, 0, stream>>>(
            x, h0o, h1o, wsA, out_yh0, BC);
    }
    // ---- level 2: rowdfilt ll(256x256) -> lo2/hi2 (256x128)
    {
        int total = BC * 256 * 64;
        rowdfilt_pair<<<(total + BLK - 1) / BLK, BLK, 0, stream>>>(
            wsA, h0a, h0b, h1a, h1b, wsB, wsC, BC, 256, 256);
    }
    // ---- level 2: coldfilt x4 -> yh1, ll2(128x128) back into wsA
    {
        int total = BC * 64 * 64;
        coldfilt_bands<<<(total + BLK - 1) / BLK, BLK, 0, stream>>>(
            wsB, wsC, h0a, h0b, h1a, h1b, wsA, out_yh1, BC, 256, 128);
    }
    // ---- level 3: rowdfilt ll2(128x128) -> lo3/hi3 (128x64)
    {
        int total = BC * 128 * 32;
        rowdfilt_pair<<<(total + BLK - 1) / BLK, BLK, 0, stream>>>(
            wsA, h0a, h0b, h1a, h1b, wsB, wsC, BC, 128, 128);
    }
    // ---- level 3: coldfilt x4 -> yh2, final ll(64x64) straight to d_out
    {
        int total = BC * 32 * 32;
        coldfilt_bands<<<(total + BLK - 1) / BLK, BLK, 0, stream>>>(
            wsB, wsC, h0a, h0b, h1a, h1b, out_ll, out_yh2, BC, 128, 64);
    }
}

// Round 2
// 221.585 us; speedup vs baseline: 1.3042x; 1.3042x over previous
//
#include <hip/hip_runtime.h>

#define SQ2F 0.70710678118654752440f

// ---------------------------------------------------------------------------
// Filter taps are compile-time constants (reference _filters() is
// deterministic); C float literals round-to-nearest identically to
// np.float32, and h1a/h1b are sign-flips/reversals of h0a — exact.
// Zeros fold out of the unrolled FMA chains.
// ---------------------------------------------------------------------------
static constexpr float H0O[5] = {-0.05f, 0.25f, 0.6f, 0.25f, -0.05f};
static constexpr float H1O[7] = {(float)(-3.0/280.0), (float)(3.0/56.0), (float)(73.0/280.0),
                                 (float)(-17.0/28.0), (float)(73.0/280.0), (float)(3.0/56.0),
                                 (float)(-3.0/280.0)};
static constexpr float H0A[10] = {0.03516384f, 0.0f, -0.08832942f, 0.23389032f, 0.76027237f,
                                  0.5875183f, 0.0f, -0.11430184f, 0.0f, 0.0f};
static constexpr float H0B[10] = {0.0f, 0.0f, -0.11430184f, 0.0f, 0.5875183f,
                                  0.76027237f, 0.23389032f, -0.08832942f, 0.0f, 0.03516384f};
static constexpr float H1A[10] = {0.0f, 0.0f, -0.11430184f, 0.0f, 0.5875183f,
                                  -0.76027237f, 0.23389032f, 0.08832942f, 0.0f, -0.03516384f};
static constexpr float H1B[10] = {-0.03516384f, 0.0f, 0.08832942f, 0.23389032f, -0.76027237f,
                                  0.5875183f, 0.0f, -0.11430184f, 0.0f, 0.0f};

__device__ __forceinline__ int symref(int t, int L) {
    // single reflection suffices for all halo ranges in this problem
    if (t < 0) t = -1 - t;
    if (t >= L) t = 2 * L - 1 - t;
    return t;
}

// ---------------------------------------------------------------------------
// Level 1: LDS-tiled fused rowfilter + colfilter + q2c + band packing.
// Block = 256 threads = 16x16 output tile (32x32 input pixels + halo).
//   x   : (BC, 256, 256)   yh0 : (BC, 6, 128, 128, 2)   ll : (BC, 256, 256)
// ---------------------------------------------------------------------------
__global__ __launch_bounds__(256) void level1_lds(
    const float* __restrict__ x,
    float* __restrict__ ll,
    float* __restrict__ yh0)
{
    const int H = 256, W = 256, H2 = 128, W2 = 128;
    __shared__ float Xs[38][39];   // input tile, reflected at load
    __shared__ float Lo[38][33];   // row-filtered (5-tap) at tile pixel cols
    __shared__ float Hi[38][33];   // row-filtered (7-tap)

    int tid = threadIdx.x;
    int bx  = blockIdx.x;
    int tj = bx & 7, ti = (bx >> 3) & 7, bc = bx >> 6;
    int i0 = ti * 16, j0 = tj * 16;
    int gr0 = 2 * i0 - 3, gc0 = 2 * j0 - 3;
    const float* xb = x + (size_t)bc * H * W;

    // ---- stage 0: coalesced load of 38x38 input region (reflection at load)
    for (int p = tid; p < 38 * 38; p += 256) {
        int r = p / 38, c = p - r * 38;
        Xs[r][c] = xb[(size_t)symref(gr0 + r, H) * W + symref(gc0 + c, W)];
    }
    __syncthreads();

    // ---- stage 1: row filters for 38 rows x 32 pixel cols
    // lo(q) = sum_t H0O[t]*x[q+2-t]  -> local col (c+5-t)
    // hi(q) = sum_t H1O[t]*x[q+3-t]  -> local col (c+6-t)
    for (int p = tid; p < 38 * 32; p += 256) {
        int c = p / 38, r = p - c * 38;   // r fastest: stride-39 LDS reads, conflict-free
        float l = 0.f, h = 0.f;
        #pragma unroll
        for (int t = 0; t < 5; t++) l += H0O[t] * Xs[r][c + 5 - t];
        #pragma unroll
        for (int t = 0; t < 7; t++) h += H1O[t] * Xs[r][c + 6 - t];
        Lo[r][c] = l;
        Hi[r][c] = h;
    }
    __syncthreads();

    // ---- stage 2: column filters, one output (i,j) per thread
    int lj = tid & 15, li = tid >> 4;
    int i = i0 + li, j = j0 + lj;

    float lo0[8], lo1[8], hi0[8], hi1[8];   // raw rows 2i-3 .. 2i+4
    #pragma unroll
    for (int rr = 0; rr < 8; rr++) {
        lo0[rr] = Lo[2 * li + rr][2 * lj];
        lo1[rr] = Lo[2 * li + rr][2 * lj + 1];
        hi0[rr] = Hi[2 * li + rr][2 * lj];
        hi1[rr] = Hi[2 * li + rr][2 * lj + 1];
    }

    float ll00=0,ll01=0,ll10=0,ll11=0, hl00=0,hl01=0,hl10=0,hl11=0;
    #pragma unroll
    for (int t = 0; t < 5; t++) {
        ll00 += H0O[t]*lo0[5-t]; ll01 += H0O[t]*lo1[5-t];
        ll10 += H0O[t]*lo0[6-t]; ll11 += H0O[t]*lo1[6-t];
        hl00 += H0O[t]*hi0[5-t]; hl01 += H0O[t]*hi1[5-t];
        hl10 += H0O[t]*hi0[6-t]; hl11 += H0O[t]*hi1[6-t];
    }
    float lh00=0,lh01=0,lh10=0,lh11=0, hh00=0,hh01=0,hh10=0,hh11=0;
    #pragma unroll
    for (int t = 0; t < 7; t++) {
        lh00 += H1O[t]*lo0[6-t]; lh01 += H1O[t]*lo1[6-t];
        lh10 += H1O[t]*lo0[7-t]; lh11 += H1O[t]*lo1[7-t];
        hh00 += H1O[t]*hi0[6-t]; hh01 += H1O[t]*hi1[6-t];
        hh10 += H1O[t]*hi0[7-t]; hh11 += H1O[t]*hi1[7-t];
    }

    float* llb = ll + (size_t)bc * H * W;
    llb[(size_t)(2*i)*W   + 2*j]     = ll00;
    llb[(size_t)(2*i)*W   + 2*j + 1] = ll01;
    llb[(size_t)(2*i+1)*W + 2*j]     = ll10;
    llb[(size_t)(2*i+1)*W + 2*j + 1] = ll11;

    float* yb = yh0 + (size_t)bc * 6 * H2 * W2 * 2;
    size_t pix = ((size_t)i * W2 + j) * 2;
    size_t bs  = (size_t)H2 * W2 * 2;
    {
        float a = SQ2F*lh00, b = SQ2F*lh01, c = SQ2F*lh10, d = SQ2F*lh11;
        yb[0*bs + pix] = a - d; yb[0*bs + pix + 1] = b + c;
        yb[5*bs + pix] = a + d; yb[5*bs + pix + 1] = b - c;
    }
    {
        float a = SQ2F*hh00, b = SQ2F*hh01, c = SQ2F*hh10, d = SQ2F*hh11;
        yb[1*bs + pix] = a - d; yb[1*bs + pix + 1] = b + c;
        yb[4*bs + pix] = a + d; yb[4*bs + pix + 1] = b - c;
    }
    {
        float a = SQ2F*hl00, b = SQ2F*hl01, c = SQ2F*hl10, d = SQ2F*hl11;
        yb[2*bs + pix] = a - d; yb[2*bs + pix + 1] = b + c;
        yb[3*bs + pix] = a + d; yb[3*bs + pix + 1] = b - c;
    }
}

// ---------------------------------------------------------------------------
// Levels 2/3 fused: rowdfilt pair (lo/hi) in LDS + coldfilt x4 + q2c + bands.
// Block = 256 threads = 16x16 output tile.
//   X     : (BC, R, C)          ll input
//   llout : (BC, R/2, C/2)      next-level ll (or final ll)
//   yh    : (BC, 6, R/4, C/4, 2)
// ---------------------------------------------------------------------------
__global__ __launch_bounds__(256) void level_fused(
    const float* __restrict__ X,
    float* __restrict__ llout,
    float* __restrict__ yh,
    int R, int C, int nbi, int nbj)
{
    __shared__ float Xs[80][81];   // 25.9 KB input tile (reflected at load)
    __shared__ float Lo[80][33];   // rowdfilt lowpass, 10.6 KB
    __shared__ float Hi[80][33];   // rowdfilt highpass

    int tid = threadIdx.x;
    int bx  = blockIdx.x;
    int tj = bx % nbj; int ti = (bx / nbj) % nbi; int bc = bx / (nbj * nbi);
    int i0 = ti * 16, j0 = tj * 16;
    int gr0 = 4 * i0 - 8, gc0 = 4 * j0 - 8;
    const float* Xb = X + (size_t)bc * R * C;

    // ---- stage 0: coalesced load of 80x80 region
    for (int p = tid; p < 80 * 80; p += 256) {
        int r = p / 80, c = p - r * 80;
        Xs[r][c] = Xb[(size_t)symref(gr0 + r, R) * C + symref(gc0 + c, C)];
    }
    __syncthreads();

    // ---- stage 1: rowdfilt pair, 80 rows x 16 col-pairs
    // a[n] = sum_t hX_b[t]*X[4n+11-2t] (local 4nl+19-2t), b[n] = sum_t hX_a[t]*X[4n+10-2t]
    for (int p = tid; p < 80 * 16; p += 256) {
        int nl = p / 80, r = p - nl * 80;   // r fastest: stride-81 LDS reads, conflict-free
        float v[20];
        #pragma unroll
        for (int k = 0; k < 20; k++) v[k] = Xs[r][4 * nl + k];
        float aLo = 0.f, bLo = 0.f, aHi = 0.f, bHi = 0.f;
        #pragma unroll
        for (int t = 0; t < 10; t++) {
            float vo = v[19 - 2 * t], ve = v[18 - 2 * t];
            aLo += H0B[t] * vo; bLo += H0A[t] * ve;
            aHi += H1B[t] * vo; bHi += H1A[t] * ve;
        }
        Lo[r][2*nl]   = aLo;  // lowpass : ev=a, od=b
        Lo[r][2*nl+1] = bLo;
        Hi[r][2*nl]   = bHi;  // highpass: ev=b, od=a
        Hi[r][2*nl+1] = aHi;
    }
    __syncthreads();

    // ---- stage 2: coldfilt x4 + q2c, one output (i,j) per thread
    int R4 = R >> 2, Wq = C >> 2, C2 = C >> 1;
    int lj = tid & 15, li = tid >> 4;
    int i = i0 + li, j = j0 + lj;

    float ll_[2][2], lh_[2][2], hl_[2][2], hh_[2][2];
    #pragma unroll
    for (int cc = 0; cc < 2; cc++) {
        int c = 2 * lj + cc;
        float vl[20], vh[20];
        #pragma unroll
        for (int k = 0; k < 20; k++) {
            vl[k] = Lo[4 * li + k][c];
            vh[k] = Hi[4 * li + k][c];
        }
        float a_ll=0,b_ll=0,a_lh=0,b_lh=0,a_hl=0,b_hl=0,a_hh=0,b_hh=0;
        #pragma unroll
        for (int t = 0; t < 10; t++) {
            float vo_l = vl[19 - 2*t], ve_l = vl[18 - 2*t];
            float vo_h = vh[19 - 2*t], ve_h = vh[18 - 2*t];
            a_ll += H0B[t] * vo_l;  b_ll += H0A[t] * ve_l;
            a_lh += H1B[t] * vo_l;  b_lh += H1A[t] * ve_l;
            a_hl += H0B[t] * vo_h;  b_hl += H0A[t] * ve_h;
            a_hh += H1B[t] * vo_h;  b_hh += H1A[t] * ve_h;
        }
        ll_[0][cc] = a_ll; ll_[1][cc] = b_ll;  // lowpass : ev=a, od=b
        lh_[0][cc] = b_lh; lh_[1][cc] = a_lh;  // highpass: ev=b, od=a
        hl_[0][cc] = a_hl; hl_[1][cc] = b_hl;
        hh_[0][cc] = b_hh; hh_[1][cc] = a_hh;
    }

    float* llb = llout + (size_t)bc * (R >> 1) * C2;
    llb[(size_t)(2*i)*C2   + 2*j]     = ll_[0][0];
    llb[(size_t)(2*i)*C2   + 2*j + 1] = ll_[0][1];
    llb[(size_t)(2*i+1)*C2 + 2*j]     = ll_[1][0];
    llb[(size_t)(2*i+1)*C2 + 2*j + 1] = ll_[1][1];

    float* yb = yh + (size_t)bc * 6 * R4 * Wq * 2;
    size_t pix = ((size_t)i * Wq + j) * 2;
    size_t bs  = (size_t)R4 * Wq * 2;
    {
        float a = SQ2F*lh_[0][0], b = SQ2F*lh_[0][1], c = SQ2F*lh_[1][0], d = SQ2F*lh_[1][1];
        yb[0*bs + pix] = a - d; yb[0*bs + pix + 1] = b + c;
        yb[5*bs + pix] = a + d; yb[5*bs + pix + 1] = b - c;
    }
    {
        float a = SQ2F*hh_[0][0], b = SQ2F*hh_[0][1], c = SQ2F*hh_[1][0], d = SQ2F*hh_[1][1];
        yb[1*bs + pix] = a - d; yb[1*bs + pix + 1] = b + c;
        yb[4*bs + pix] = a + d; yb[4*bs + pix + 1] = b - c;
    }
    {
        float a = SQ2F*hl_[0][0], b = SQ2F*hl_[0][1], c = SQ2F*hl_[1][0], d = SQ2F*hl_[1][1];
        yb[2*bs + pix] = a - d; yb[2*bs + pix + 1] = b + c;
        yb[3*bs + pix] = a + d; yb[3*bs + pix + 1] = b - c;
    }
}

extern "C" void kernel_launch(void* const* d_in, const int* in_sizes, int n_in,
                              void* d_out, int out_size, void* d_ws, size_t ws_size,
                              hipStream_t stream) {
    const float* x = (const float*)d_in[0];
    float* out = (float*)d_out;

    const int BC = 8 * 16;  // 128

    // output layout (flat, return order): ll | yh0 | yh1 | yh2
    float* out_ll  = out;                        // 128*64*64          = 524288
    float* out_yh0 = out + 524288;               // 128*6*128*128*2    = 25165824
    float* out_yh1 = out + 25690112;             // 128*6*64*64*2      = 6291456
    float* out_yh2 = out + 31981568;             // 128*6*32*32*2      = 1572864

    // workspace: wsA = ll level-1 (32 MiB), wsB = ll level-2 (8 MiB)
    float* wsA = (float*)d_ws;
    float* wsB = wsA + 8388608;

    // ---- level 1: x -> yh0, ll(256x256) in wsA  (8x8 tiles of 16x16 outputs)
    level1_lds<<<BC * 8 * 8, 256, 0, stream>>>(x, wsA, out_yh0);

    // ---- level 2: ll(256x256) -> yh1, ll2(128x128) in wsB
    level_fused<<<BC * 4 * 4, 256, 0, stream>>>(wsA, wsB, out_yh1, 256, 256, 4, 4);

    // ---- level 3: ll2(128x128) -> yh2, final ll(64x64) to d_out
    level_fused<<<BC * 2 * 2, 256, 0, stream>>>(wsB, out_ll, out_yh2, 128, 128, 2, 2);
}